// Round 12
// baseline (359.581 us; speedup 1.0000x reference)
//
#include <hip/hip_runtime.h>
#include <hip/hip_bf16.h>

typedef unsigned short u16;
typedef unsigned int u32;
typedef __bf16 bf16x8 __attribute__((ext_vector_type(8)));
typedef float f32x4 __attribute__((ext_vector_type(4)));

__device__ __forceinline__ float bf2f(u16 h) { return __uint_as_float(((u32)h) << 16); }
__device__ __forceinline__ u16 f2bf(float f) {
    u32 u = __float_as_uint(f);
    u32 r = u + 0x7FFFu + ((u >> 16) & 1u);   // round-to-nearest-even
    return (u16)(r >> 16);
}
// HW packed f32->bf16 (RNE, identical to f2bf): 1 instruction per pair
__device__ __forceinline__ u32 cvtpk(float lo, float hi) {
    u32 r;
    asm("v_cvt_pk_bf16_f32 %0, %1, %2" : "=v"(r) : "v"(lo), "v"(hi));
    return r;
}
__device__ __forceinline__ u16 cvt1(float v) { return (u16)cvtpk(v, v); }
__device__ __forceinline__ void unpack8(const u16* p, float* b) {
    uint4 v = *(const uint4*)p;
    b[0] = bf2f((u16)(v.x & 0xFFFF)); b[1] = bf2f((u16)(v.x >> 16));
    b[2] = bf2f((u16)(v.y & 0xFFFF)); b[3] = bf2f((u16)(v.y >> 16));
    b[4] = bf2f((u16)(v.z & 0xFFFF)); b[5] = bf2f((u16)(v.z >> 16));
    b[6] = bf2f((u16)(v.w & 0xFFFF)); b[7] = bf2f((u16)(v.w >> 16));
}
__device__ __forceinline__ float ldf(int bf, const void* p, long i) {
    return bf ? bf2f(((const u16*)p)[i]) : ((const float*)p)[i];
}

// -------- detector (wave-parallel): flags[0]=1 if bf16; flags[1]=1 if edge_index int64 --------
__global__ void k_detect(const u32* __restrict__ x, const u32* __restrict__ ei, u32* __restrict__ flags) {
    int tid = threadIdx.x;   // 64 threads
    int c = 0;
    for (int i = tid; i < 256; i += 64) {
        u32 e = (x[i] >> 7) & 0xFF;
        if (e >= 96 && e <= 160) c++;
    }
#pragma unroll
    for (int d = 1; d < 64; d <<= 1) c += __shfl_xor(c, d);
    int z = (ei[2 * tid + 1] == 0u) ? 1 : 0;
#pragma unroll
    for (int d = 1; d < 64; d <<= 1) z += __shfl_xor(z, d);
    if (tid == 0) {
        flags[0] = (c >= 192) ? 1u : 0u;
        flags[1] = (z >= 48) ? 1u : 0u;
    }
}

// -------- prep: ALL transposed bf16 weights + workspace zeroing, one kernel --------
__global__ void k_prep(const void* __restrict__ fw0, const void* __restrict__ fw1,
                       const void* __restrict__ gw0, const void* __restrict__ gw1,
                       const void* __restrict__ hw0,
                       u16* __restrict__ w0t, u16* __restrict__ w1t,
                       u16* __restrict__ w0tg, u16* __restrict__ w1tg, u16* __restrict__ hw0t,
                       const u32* __restrict__ flags,
                       u32* __restrict__ z1, int nz1, u32* __restrict__ z2, int nz2) {
    int bf = (int)flags[0];
    int tid = blockIdx.x * blockDim.x + threadIdx.x;
    int stride = gridDim.x * blockDim.x;
    for (int i = tid; i < nz1; i += stride) z1[i] = 0u;
    for (int i = tid; i < nz2; i += stride) z2[i] = 0u;
    for (int i = tid; i < 128 * 128; i += stride) {
        int c = i >> 7, kp = i & 127;
        float vf = (kp < 96) ? ldf(bf, fw0, (long)(kp + 3) * 128 + c) : 0.f;
        w0t[i] = f2bf(vf);
        float vg = (kp < 96) ? ldf(bf, gw0, (long)kp * 128 + c) : 0.f;
        w0tg[i] = f2bf(vg);
    }
    for (int i = tid; i < 96 * 128; i += stride) {
        int c = i >> 7, k = i & 127;
        w1t[i]  = f2bf(ldf(bf, fw1, (long)k * 96 + c));
        w1tg[i] = f2bf(ldf(bf, gw1, (long)k * 96 + c));
    }
    for (int i = tid; i < 64 * 128; i += stride) {
        int c = i >> 7, kp = i & 127;
        float v = (kp < 96) ? ldf(bf, hw0, (long)kp * 64 + c) : 0.f;
        hw0t[i] = f2bf(v);
    }
}

// -------- k_cvt: ei -> packed u32 (src | dst<<16) eraw + dst histogram.  N <= 65536. --------
__global__ void k_cvt(const u32* __restrict__ ei, u32* __restrict__ eraw, u32* __restrict__ hist,
                      const u32* __restrict__ flags, int nE, int N) {
    u32 i64f = flags[1];
    for (long e = blockIdx.x * blockDim.x + threadIdx.x; e < nE; e += (long)gridDim.x * blockDim.x) {
        int src, dst;
        if (i64f) { src = (int)ei[2 * e]; dst = (int)ei[2 * ((long)nE + e)]; }
        else      { src = (int)ei[e];     dst = (int)ei[(long)nE + e]; }
        src = min(max(src, 0), N - 1);
        dst = min(max(dst, 0), N - 1);
        eraw[e] = (u32)src | ((u32)dst << 16);
        atomicAdd(&hist[dst], 1u);
    }
}

// -------- 2-phase parallel exclusive scan --------
__global__ __launch_bounds__(256)
void k_scanA(const u32* __restrict__ hist, u32* __restrict__ blkSum, int n) {
    __shared__ u32 red[4];
    int tid = threadIdx.x;
    int base = blockIdx.x * 1024 + tid * 4;
    u32 s = 0;
#pragma unroll
    for (int j = 0; j < 4; j++) {
        int idx = base + j;
        if (idx < n) s += hist[idx];
    }
#pragma unroll
    for (int d = 1; d < 64; d <<= 1) s += __shfl_xor(s, d);
    if ((tid & 63) == 0) red[tid >> 6] = s;
    __syncthreads();
    if (tid == 0) blkSum[blockIdx.x] = red[0] + red[1] + red[2] + red[3];
}
__global__ __launch_bounds__(256)
void k_scanC(const u32* __restrict__ hist, const u32* __restrict__ blkSum,
             u32* __restrict__ cur, u32* __restrict__ dstart, int n, u32 total) {
    __shared__ u32 a[256];
    int tid = threadIdx.x;
    a[tid] = (tid < blockIdx.x) ? blkSum[tid] : 0u;
    __syncthreads();
    for (int d = 128; d > 0; d >>= 1) {
        if (tid < d) a[tid] += a[tid + d];
        __syncthreads();
    }
    u32 boff = a[0];
    __syncthreads();
    int base = blockIdx.x * 1024 + tid * 4;
    u32 e[4];
    u32 ts = 0;
#pragma unroll
    for (int j = 0; j < 4; j++) {
        int idx = base + j;
        e[j] = (idx < n) ? hist[idx] : 0u;
        ts += e[j];
    }
    a[tid] = ts;
    __syncthreads();
    for (int d = 1; d < 256; d <<= 1) {
        u32 t = (tid >= d) ? a[tid - d] : 0u;
        __syncthreads();
        a[tid] += t;
        __syncthreads();
    }
    u32 off = boff + a[tid] - ts;
#pragma unroll
    for (int j = 0; j < 4; j++) {
        int idx = base + j;
        if (idx < n) { cur[idx] = off; dstart[idx] = off; off += e[j]; }
    }
    if (blockIdx.x == 0 && tid == 0) dstart[n] = total;
}

__global__ void k_scatter(const u32* __restrict__ eraw, u32* __restrict__ cur,
                          u32* __restrict__ edges, int nE) {
    for (long e = blockIdx.x * blockDim.x + threadIdx.x; e < nE; e += (long)gridDim.x * blockDim.x) {
        u32 ed = eraw[e];
        u32 p = atomicAdd(&cur[ed >> 16], 1u);
        edges[p] = ed;
    }
}

// -------- K_YD: fused per-node precompute --------
__global__ __launch_bounds__(256)
void k_yd(const void* __restrict__ x, const void* __restrict__ pos,
          const u16* __restrict__ w0t, const u16* __restrict__ hw0t,
          const void* __restrict__ hb0, const void* __restrict__ hw1, const void* __restrict__ hb1,
          const void* __restrict__ fw0, const void* __restrict__ fb0,
          u16* __restrict__ yu, float* __restrict__ vbO,
          const u32* __restrict__ flags, int N)
{
    const int bf = (int)flags[0];
    __shared__ __align__(16) char arena[16384];
    __shared__ float posS[64][4];
    __shared__ float h1S[64][68];
    __shared__ float w0rS[384];
    __shared__ float b0fS[128];
    __shared__ float hb0S[64];
    __shared__ float hw1S[192];
    __shared__ float hb1S[3];
    int tid = threadIdx.x;
    for (int i = tid; i < 384; i += 256) w0rS[i] = ldf(bf, fw0, i);
    if (tid < 128) b0fS[tid] = ldf(bf, fb0, tid);
    if (tid < 64)  hb0S[tid] = ldf(bf, hb0, tid);
    if (tid < 192) hw1S[tid] = ldf(bf, hw1, tid);
    if (tid < 3)   hb1S[tid] = ldf(bf, hb1, tid);
    __syncthreads();

    const int lane = tid & 63;
    const int wid  = tid >> 6;
    const int mrow0 = wid * 16;
    const int r16  = lane & 15;
    const int arow = mrow0 + r16;
    const int kgrp = lane >> 4;
    const int srow = tid >> 2;
    const int q = tid & 3;
    const int ssw = (srow & 7) << 4;

    int ntile = (N + 63) / 64;
    for (int t = blockIdx.x; t < ntile; t += gridDim.x) {
        {   // stage x rows -> swizzled arena bf16; pos -> posS
            int n = t * 64 + srow;
            if (tid < 64) {
                int n2 = t * 64 + tid;
                posS[tid][0] = (n2 < N) ? ldf(bf, pos, (long)n2 * 3 + 0) : 0.f;
                posS[tid][1] = (n2 < N) ? ldf(bf, pos, (long)n2 * 3 + 1) : 0.f;
                posS[tid][2] = (n2 < N) ? ldf(bf, pos, (long)n2 * 3 + 2) : 0.f;
            }
            if (n < N) {
                if (bf) {
                    const uint4* ar = (const uint4*)((const u16*)x + (size_t)n * 96);
#pragma unroll
                    for (int j = 0; j < 3; j++) {
                        int c = q * 3 + j;
                        *(uint4*)(arena + srow * 256 + ((c * 16) ^ ssw)) = ar[c];
                    }
                } else {
                    const float4* xp = (const float4*)((const float*)x + (size_t)n * 96);
#pragma unroll
                    for (int j = 0; j < 3; j++) {
                        int c = q * 3 + j;
                        float4 v0 = xp[2 * c], v1 = xp[2 * c + 1];
                        *(uint4*)(arena + srow * 256 + ((c * 16) ^ ssw)) =
                            make_uint4(cvtpk(v0.x, v0.y), cvtpk(v0.z, v0.w),
                                       cvtpk(v1.x, v1.y), cvtpk(v1.z, v1.w));
                    }
                }
            } else {
#pragma unroll
                for (int j = 0; j < 3; j++)
                    *(uint4*)(arena + srow * 256 + (((q * 3 + j) * 16) ^ ssw)) = make_uint4(0u, 0u, 0u, 0u);
            }
        }
        __syncthreads();
        int sw = (arow & 7) << 4;
        bf16x8 a0 = *(const bf16x8*)(arena + arow * 256 + ((0   + kgrp * 16) ^ sw));
        bf16x8 a1 = *(const bf16x8*)(arena + arow * 256 + ((64  + kgrp * 16) ^ sw));
        bf16x8 a2 = *(const bf16x8*)(arena + arow * 256 + ((128 + kgrp * 16) ^ sw));
        // ---- GEMM-delta layer1: h1 = relu(x @ hw0 + hb0), N=64 ----
        f32x4 accd[4];
#pragma unroll
        for (int nt = 0; nt < 4; nt++) {
#pragma unroll
            for (int r = 0; r < 4; r++) accd[nt][r] = 0.f;
        }
#pragma unroll
        for (int nt = 0; nt < 4; nt++) {
            const u16* wp = hw0t + (long)(nt * 16 + r16) * 128 + kgrp * 8;
            accd[nt] = __builtin_amdgcn_mfma_f32_16x16x32_bf16(a0, *(const bf16x8*)(wp),      accd[nt], 0, 0, 0);
            accd[nt] = __builtin_amdgcn_mfma_f32_16x16x32_bf16(a1, *(const bf16x8*)(wp + 32), accd[nt], 0, 0, 0);
            accd[nt] = __builtin_amdgcn_mfma_f32_16x16x32_bf16(a2, *(const bf16x8*)(wp + 64), accd[nt], 0, 0, 0);
        }
#pragma unroll
        for (int nt = 0; nt < 4; nt++) {
            int col = nt * 16 + r16;
#pragma unroll
            for (int r = 0; r < 4; r++)
                h1S[mrow0 + kgrp * 4 + r][col] = fmaxf(accd[nt][r] + hb0S[col], 0.f);
        }
        // ---- GEMM-y: y = x @ w0t (f-MLP cols), N=128 ----
        f32x4 acc[8];
#pragma unroll
        for (int nt = 0; nt < 8; nt++) {
#pragma unroll
            for (int r = 0; r < 4; r++) acc[nt][r] = 0.f;
        }
#pragma unroll
        for (int nt = 0; nt < 8; nt++) {
            const u16* wp = w0t + (long)(nt * 16 + r16) * 128 + kgrp * 8;
            acc[nt] = __builtin_amdgcn_mfma_f32_16x16x32_bf16(a0, *(const bf16x8*)(wp),      acc[nt], 0, 0, 0);
            acc[nt] = __builtin_amdgcn_mfma_f32_16x16x32_bf16(a1, *(const bf16x8*)(wp + 32), acc[nt], 0, 0, 0);
            acc[nt] = __builtin_amdgcn_mfma_f32_16x16x32_bf16(a2, *(const bf16x8*)(wp + 64), acc[nt], 0, 0, 0);
        }
        __syncthreads();   // h1S complete
        // ---- delta layer2 (64->3) + vb epilogue ----
        {
            int nl = tid >> 2;
            int n = t * 64 + nl;
            float d0 = hb1S[0], d1 = hb1S[1], d2 = hb1S[2];
#pragma unroll 8
            for (int j = 0; j < 64; j++) {
                float hv = h1S[nl][j];
                d0 += hv * hw1S[j * 3 + 0];
                d1 += hv * hw1S[j * 3 + 1];
                d2 += hv * hw1S[j * 3 + 2];
            }
            float p0 = d0 - posS[nl][0], p1 = d1 - posS[nl][1], p2 = d2 - posS[nl][2];
            if (n < N) {
                float* vrow = vbO + (size_t)n * 128 + q * 32;
#pragma unroll
                for (int c4 = 0; c4 < 8; c4++) {
                    float4 o;
#pragma unroll
                    for (int k = 0; k < 4; k++) {
                        int col = q * 32 + c4 * 4 + k;
                        float v = p0 * w0rS[col] + p1 * w0rS[128 + col] + p2 * w0rS[256 + col] + b0fS[col];
                        ((float*)&o)[k] = v;
                    }
                    *(float4*)(vrow + c4 * 4) = o;
                }
            }
        }
        // ---- yu epilogue: yu = y + pos . w0r ----
#pragma unroll
        for (int nt = 0; nt < 8; nt++) {
            int col = nt * 16 + r16;
            float wr0 = w0rS[col], wr1 = w0rS[128 + col], wr2 = w0rS[256 + col];
#pragma unroll
            for (int r = 0; r < 4; r++) {
                int row = mrow0 + kgrp * 4 + r;
                int n2 = t * 64 + row;
                if (n2 < N) {
                    float u = posS[row][0] * wr0 + posS[row][1] * wr1 + posS[row][2] * wr2;
                    yu[(size_t)n2 * 128 + col] = cvt1(acc[nt][r] + u);
                }
            }
        }
        __syncthreads();
    }
}

// -------- K2: edge MLP: h = relu(yu[src] + vb[dst]); GEMM2 MFMA; zero atomics --------
// edges packed u32: src = e & 0xFFFF, dst = e >> 16 (N <= 65536)
__global__ __launch_bounds__(256)
void k_edge(const u16* __restrict__ yu, const float4* __restrict__ vb,
            const u32* __restrict__ edges, const u16* __restrict__ w1t,
            const void* __restrict__ fb1, const u32* __restrict__ flags,
            u16* __restrict__ agg, u16* __restrict__ pbuf, int nE)
{
    const int bf = (int)flags[0];
    __shared__ __align__(16) u16 w1S[96 * 128];      // 24576 B, XOR-swizzled rows of 256 B
    __shared__ float b1s[96];
    __shared__ int dstS[4][16];
    __shared__ __align__(16) u16 outS[4][16 * 98];   // bf16 out, stride 98
    int tid = threadIdx.x;
    for (int i = tid; i < 96 * 64; i += 256) {
        int col = i >> 6, kp = i & 63;
        u32 v = ((const u32*)w1t)[i];
        *(u32*)((char*)w1S + col * 256 + ((kp * 4) ^ ((col & 7) << 4))) = v;
    }
    if (tid < 96) b1s[tid] = ldf(bf, fb1, tid);
    __syncthreads();   // one-time staging only

    const int lane = tid & 63;
    const int wid  = tid >> 6;
    const int r16  = lane & 15;
    const int kgrp = lane >> 4;
    const int ntile = (nE + 15) / 16;
    const size_t tailSlot = (size_t)ntile * 96;
    u16* const outSw = outS[wid];

    const int stride = (int)gridDim.x * 4;
    int t = (int)blockIdx.x * 4 + wid;

    // pipeline regs
    u32 ce = 0u, ne = 0u;
    uint4 G[4];                        // yu fragments for tile t

    auto issueGather = [&](u32 src) {
        const u16* yp = yu + (size_t)src * 128 + kgrp * 8;
#pragma unroll
        for (int f = 0; f < 4; f++) G[f] = *(const uint4*)(yp + f * 32);
    };

    if (t < ntile) {
        long E = min((long)t * 16 + r16, (long)nE - 1);
        ce = edges[E];
        issueGather(ce & 0xFFFFu);
        int tn = t + stride;
        if (tn < ntile) {
            long En = min((long)tn * 16 + r16, (long)nE - 1);
            ne = edges[En];
        }
    }

    for (; t < ntile; t += stride) {
        asm volatile("" ::: "memory");
        if (kgrp == 3) dstS[wid][r16] = (int)(ce >> 16);
        // neighbor dsts for boundary-run classification
        int dprevV = -1, dnextV = -1;
        {
            long e0 = (long)t * 16;
            if (e0 > 0) dprevV = (int)(edges[e0 - 1] >> 16);
            if (e0 + 16 < (long)nE) dnextV = (int)(edges[e0 + 16] >> 16);
        }
        // ---- h fragments: relu(yu + vb), lane-local; vb JIT loads (L1-resident runs) ----
        const float4* vbp = vb + (size_t)(ce >> 16) * 32 + kgrp * 2;
        bf16x8 hf[4];
#pragma unroll
        for (int f = 0; f < 4; f++) {
            float4 v0 = vbp[f * 8], v1 = vbp[f * 8 + 1];
            u32 w0 = G[f].x, w1 = G[f].y, w2 = G[f].z, w3 = G[f].w;
            u32 hw[4];
            hw[0] = cvtpk(fmaxf(bf2f((u16)(w0 & 0xFFFF)) + v0.x, 0.f),
                          fmaxf(bf2f((u16)(w0 >> 16))    + v0.y, 0.f));
            hw[1] = cvtpk(fmaxf(bf2f((u16)(w1 & 0xFFFF)) + v0.z, 0.f),
                          fmaxf(bf2f((u16)(w1 >> 16))    + v0.w, 0.f));
            hw[2] = cvtpk(fmaxf(bf2f((u16)(w2 & 0xFFFF)) + v1.x, 0.f),
                          fmaxf(bf2f((u16)(w2 >> 16))    + v1.y, 0.f));
            hw[3] = cvtpk(fmaxf(bf2f((u16)(w3 & 0xFFFF)) + v1.z, 0.f),
                          fmaxf(bf2f((u16)(w3 >> 16))    + v1.w, 0.f));
            uint4 hv = make_uint4(hw[0], hw[1], hw[2], hw[3]);
            hf[f] = *(const bf16x8*)&hv;
        }
        // ---- G is dead: issue next tile's gathers + indices (depth-1 pipeline) ----
        u32 c2e = ne;
        {
            int tn = t + stride;
            if (tn < ntile) {
                issueGather(c2e & 0xFFFFu);
                int tn2 = tn + stride;
                if (tn2 < ntile) {
                    long E2 = min((long)tn2 * 16 + r16, (long)nE - 1);
                    ne = edges[E2];
                }
            }
        }
        // ---- GEMM2: e2 = h @ W1 (K=128, N=96), W1 from swizzled LDS ----
        f32x4 acc2[6];
#pragma unroll
        for (int nt = 0; nt < 6; nt++) {
#pragma unroll
            for (int r = 0; r < 4; r++) acc2[nt][r] = 0.f;
        }
#pragma unroll
        for (int nt = 0; nt < 6; nt++) {
            int colr = nt * 16 + r16;
            const char* wb = (const char*)w1S + colr * 256;
            int csw = (colr & 7) << 4;
            acc2[nt] = __builtin_amdgcn_mfma_f32_16x16x32_bf16(hf[0], *(const bf16x8*)(wb + ((kgrp * 16)       ^ csw)), acc2[nt], 0, 0, 0);
            acc2[nt] = __builtin_amdgcn_mfma_f32_16x16x32_bf16(hf[1], *(const bf16x8*)(wb + ((kgrp * 16 + 64)  ^ csw)), acc2[nt], 0, 0, 0);
            acc2[nt] = __builtin_amdgcn_mfma_f32_16x16x32_bf16(hf[2], *(const bf16x8*)(wb + ((kgrp * 16 + 128) ^ csw)), acc2[nt], 0, 0, 0);
            acc2[nt] = __builtin_amdgcn_mfma_f32_16x16x32_bf16(hf[3], *(const bf16x8*)(wb + ((kgrp * 16 + 192) ^ csw)), acc2[nt], 0, 0, 0);
        }
        // out (bf16) -> wave-local stride-98 overlay
#pragma unroll
        for (int nt = 0; nt < 6; nt++) {
            int col = nt * 16 + r16;
#pragma unroll
            for (int r = 0; r < 4; r++) {
                int row = kgrp * 4 + r;
                outSw[row * 98 + col] = cvt1(acc2[nt][r]);
            }
        }
        // ---- run-scan: plain stores (complete runs -> agg; boundary -> pbuf) ----
        {
            int d0s = dstS[wid][0], d15s = dstS[wid][15];
            bool extL = (dprevV == d0s);
            bool extR = (dnextV == d15s);
#pragma unroll
            for (int p = 0; p < 2; p++) {
                int col = p * 64 + lane;
                if (p == 0 || lane < 32) {
                    float b1c = b1s[col];
                    int curd = d0s;
                    int r0 = 0;
                    float m = bf2f(outSw[col]);
#pragma unroll
                    for (int row = 1; row < 16; row++) {
                        float v = bf2f(outSw[row * 98 + col]);
                        int d = dstS[wid][row];
                        if (d != curd) {
                            if (r0 == 0 && extL) pbuf[(size_t)t * 96 + col] = cvt1(m);
                            else agg[(size_t)curd * 96 + col] = cvt1(m + b1c);
                            curd = d; r0 = row; m = v;
                        } else m = fmaxf(m, v);
                    }
                    bool pl = (r0 == 0) && extL;
                    if (pl || extR) {
                        size_t slot = (r0 == 0) ? 0 : tailSlot;
                        pbuf[slot + (size_t)t * 96 + col] = cvt1(m);
                    } else agg[(size_t)curd * 96 + col] = cvt1(m + b1c);
                }
            }
        }
        ce = c2e;
    }
}

// -------- K3: out = x + mlp_g(agg)  (96 -> 128 relu -> 96), MFMA; inline pbuf merge --------
__global__ __launch_bounds__(256)
void k_node(const void* __restrict__ x, const u16* __restrict__ agg,
            const u32* __restrict__ dstart, const u16* __restrict__ pbuf,
            const u16* __restrict__ w0tg, const u16* __restrict__ w1tg,
            const void* __restrict__ gb0, const void* __restrict__ gb1,
            const void* __restrict__ fb1,
            void* __restrict__ out, const u32* __restrict__ flags, int N, int nE)
{
    const int bf = (int)flags[0];
    __shared__ __align__(16) char arena[32768];
    __shared__ float b0s[128];
    __shared__ float b1s[96];
    __shared__ float b1f[96];
    int tid = threadIdx.x;
    if (tid < 128) b0s[tid] = ldf(bf, gb0, tid);
    if (tid < 96)  b1s[tid] = ldf(bf, gb1, tid);
    if (tid < 96)  b1f[tid] = ldf(bf, fb1, tid);
    __syncthreads();

    const int lane = tid & 63;
    const int wid  = tid >> 6;
    const int mrow0 = wid * 16;
    const int arow = mrow0 + (lane & 15);
    const int kgrp = lane >> 4;
    const int srow = tid >> 2;
    const int q = tid & 3;
    const int ssw = (srow & 7) << 4;
    const int ntileE = (nE + 15) / 16;

    float b0v[8];
#pragma unroll
    for (int nt = 0; nt < 8; nt++) b0v[nt] = b0s[nt * 16 + (lane & 15)];

    auto outOff = [](int row, int col) {
        int j = row & 15, w2 = row >> 4;
        int base = (j < 8) ? (w2 * 4096 + j * 512) : (16384 + w2 * 4096 + (j - 8) * 512);
        return base + ((col ^ (((row >> 2) & 3) << 4)) << 2);
    };

    int ntile = (N + 63) / 64;
    for (int t = blockIdx.x; t < ntile; t += gridDim.x) {
        asm volatile("" ::: "memory");
        {   // stage agg row: single-tile/empty -> agg; multi-tile -> merge pbuf partials (+fb1)
            int n = t * 64 + srow;
            if (n < N) {
                u32 s = dstart[n], e = dstart[n + 1];
                int t0 = (int)(s >> 4);
                int t1 = (e > s) ? (int)((e - 1) >> 4) : t0;
                if (e > s && t0 != t1) {
                    const u16* pH = pbuf;
                    const u16* pT = pbuf + (size_t)ntileE * 96;
                    const u16* first = ((s & 15u) == 0u) ? pH : pT;
#pragma unroll
                    for (int j = 0; j < 3; j++) {
                        int c = q * 3 + j;
                        float mf[8];
                        unpack8(first + (size_t)t0 * 96 + c * 8, mf);
                        for (int tt = t0 + 1; tt <= t1; tt++) {
                            float tf[8];
                            unpack8(pH + (size_t)tt * 96 + c * 8, tf);
#pragma unroll
                            for (int k = 0; k < 8; k++) mf[k] = fmaxf(mf[k], tf[k]);
                        }
                        uint4 o;
                        o.x = cvtpk(mf[0] + b1f[c * 8 + 0], mf[1] + b1f[c * 8 + 1]);
                        o.y = cvtpk(mf[2] + b1f[c * 8 + 2], mf[3] + b1f[c * 8 + 3]);
                        o.z = cvtpk(mf[4] + b1f[c * 8 + 4], mf[5] + b1f[c * 8 + 5]);
                        o.w = cvtpk(mf[6] + b1f[c * 8 + 6], mf[7] + b1f[c * 8 + 7]);
                        *(uint4*)(arena + srow * 256 + ((c * 16) ^ ssw)) = o;
                    }
                } else {
                    const uint4* ar = (const uint4*)(agg + (size_t)n * 96);
#pragma unroll
                    for (int j = 0; j < 3; j++) {
                        int c = q * 3 + j;
                        *(uint4*)(arena + srow * 256 + ((c * 16) ^ ssw)) = ar[c];
                    }
                }
            } else {
#pragma unroll
                for (int j = 0; j < 3; j++)
                    *(uint4*)(arena + srow * 256 + (((q * 3 + j) * 16) ^ ssw)) = make_uint4(0u, 0u, 0u, 0u);
            }
        }
        __syncthreads();
        int sw = (arow & 7) << 4;
        bf16x8 a0 = *(const bf16x8*)(arena + arow * 256 + ((0   + kgrp * 16) ^ sw));
        bf16x8 a1 = *(const bf16x8*)(arena + arow * 256 + ((64  + kgrp * 16) ^ sw));
        bf16x8 a2 = *(const bf16x8*)(arena + arow * 256 + ((128 + kgrp * 16) ^ sw));
        f32x4 acc[8];
#pragma unroll
        for (int nt = 0; nt < 8; nt++) {
#pragma unroll
            for (int r = 0; r < 4; r++) acc[nt][r] = 0.f;
        }
#pragma unroll
        for (int nt = 0; nt < 8; nt++) {
            const u16* wp = w0tg + (long)(nt * 16 + (lane & 15)) * 128 + kgrp * 8;
            acc[nt] = __builtin_amdgcn_mfma_f32_16x16x32_bf16(a0, *(const bf16x8*)(wp),      acc[nt], 0, 0, 0);
            acc[nt] = __builtin_amdgcn_mfma_f32_16x16x32_bf16(a1, *(const bf16x8*)(wp + 32), acc[nt], 0, 0, 0);
            acc[nt] = __builtin_amdgcn_mfma_f32_16x16x32_bf16(a2, *(const bf16x8*)(wp + 64), acc[nt], 0, 0, 0);
        }
#pragma unroll
        for (int nt = 0; nt < 8; nt++) {
            int col = nt * 16 + (lane & 15);
#pragma unroll
            for (int r = 0; r < 4; r++) {
                int row = mrow0 + kgrp * 4 + r;
                float hv = fmaxf(acc[nt][r] + b0v[nt], 0.f);
                *(u16*)(arena + 16384 + row * 256 + ((col * 2) ^ ((row & 7) << 4))) = cvt1(hv);
            }
        }
        bf16x8 h0 = *(const bf16x8*)(arena + 16384 + arow * 256 + ((0   + kgrp * 16) ^ sw));
        bf16x8 h1 = *(const bf16x8*)(arena + 16384 + arow * 256 + ((64  + kgrp * 16) ^ sw));
        bf16x8 h2 = *(const bf16x8*)(arena + 16384 + arow * 256 + ((128 + kgrp * 16) ^ sw));
        bf16x8 h3 = *(const bf16x8*)(arena + 16384 + arow * 256 + ((192 + kgrp * 16) ^ sw));
        f32x4 acc2[6];
#pragma unroll
        for (int nt = 0; nt < 6; nt++) {
#pragma unroll
            for (int r = 0; r < 4; r++) acc2[nt][r] = 0.f;
        }
#pragma unroll
        for (int nt = 0; nt < 6; nt++) {
            const u16* wp = w1tg + (long)(nt * 16 + (lane & 15)) * 128 + kgrp * 8;
            acc2[nt] = __builtin_amdgcn_mfma_f32_16x16x32_bf16(h0, *(const bf16x8*)(wp),      acc2[nt], 0, 0, 0);
            acc2[nt] = __builtin_amdgcn_mfma_f32_16x16x32_bf16(h1, *(const bf16x8*)(wp + 32), acc2[nt], 0, 0, 0);
            acc2[nt] = __builtin_amdgcn_mfma_f32_16x16x32_bf16(h2, *(const bf16x8*)(wp + 64), acc2[nt], 0, 0, 0);
            acc2[nt] = __builtin_amdgcn_mfma_f32_16x16x32_bf16(h3, *(const bf16x8*)(wp + 96), acc2[nt], 0, 0, 0);
        }
#pragma unroll
        for (int nt = 0; nt < 6; nt++) {
            int col = nt * 16 + (lane & 15);
#pragma unroll
            for (int r = 0; r < 4; r++) {
                int row = mrow0 + kgrp * 4 + r;
                *(float*)(arena + outOff(row, col)) = acc2[nt][r];
            }
        }
        __syncthreads();
        {
            int n = t * 64 + srow;
            if (n < N) {
                float v[24];
#pragma unroll
                for (int c = 0; c < 24; c++) v[c] = *(const float*)(arena + outOff(srow, q * 24 + c));
                if (bf) {
                    u16* orow = (u16*)out + (size_t)n * 96 + q * 24;
#pragma unroll
                    for (int j = 0; j < 3; j++) {
                        float xv[8];
                        unpack8((const u16*)x + (size_t)n * 96 + q * 24 + j * 8, xv);
                        uint4 o;
                        o.x = cvtpk(xv[0] + v[j * 8 + 0] + b1s[q * 24 + j * 8 + 0],
                                    xv[1] + v[j * 8 + 1] + b1s[q * 24 + j * 8 + 1]);
                        o.y = cvtpk(xv[2] + v[j * 8 + 2] + b1s[q * 24 + j * 8 + 2],
                                    xv[3] + v[j * 8 + 3] + b1s[q * 24 + j * 8 + 3]);
                        o.z = cvtpk(xv[4] + v[j * 8 + 4] + b1s[q * 24 + j * 8 + 4],
                                    xv[5] + v[j * 8 + 5] + b1s[q * 24 + j * 8 + 5]);
                        o.w = cvtpk(xv[6] + v[j * 8 + 6] + b1s[q * 24 + j * 8 + 6],
                                    xv[7] + v[j * 8 + 7] + b1s[q * 24 + j * 8 + 7]);
                        *(uint4*)(orow + j * 8) = o;
                    }
                } else {
                    const float* xr = (const float*)x + (size_t)n * 96 + q * 24;
                    float* orow = (float*)out + (size_t)n * 96 + q * 24;
#pragma unroll
                    for (int j = 0; j < 6; j++) {
                        float4 xv = ((const float4*)xr)[j];
                        float4 o;
                        o.x = xv.x + v[4 * j + 0] + b1s[q * 24 + 4 * j + 0];
                        o.y = xv.y + v[4 * j + 1] + b1s[q * 24 + 4 * j + 1];
                        o.z = xv.z + v[4 * j + 2] + b1s[q * 24 + 4 * j + 2];
                        o.w = xv.w + v[4 * j + 3] + b1s[q * 24 + 4 * j + 3];
                        ((float4*)orow)[j] = o;
                    }
                }
            }
        }
        __syncthreads();
    }
}

extern "C" void kernel_launch(void* const* d_in, const int* in_sizes, int n_in,
                              void* d_out, int out_size, void* d_ws, size_t ws_size,
                              hipStream_t stream) {
    const void* x   = d_in[0];
    const void* pos = d_in[1];
    const void* ei  = d_in[2];
    const void* hw0 = d_in[3];
    const void* hb0 = d_in[4];
    const void* hw1 = d_in[5];
    const void* hb1 = d_in[6];
    const void* fw0 = d_in[7];
    const void* fb0 = d_in[8];
    const void* fw1 = d_in[9];
    const void* fb1 = d_in[10];
    const void* gw0 = d_in[11];
    const void* gb0 = d_in[12];
    const void* gw1 = d_in[13];
    const void* gb1 = d_in[14];

    int N  = in_sizes[0] / 96;   // 50000  (< 65536: u16 packing valid)
    int nE = in_sizes[2] / 2;    // 800000
    int ntileE = (nE + 15) / 16; // 50000
    int nBlkScan = (N + 1023) / 1024;  // 49 (<= 256 required by k_scanC)

    // workspace layout (256B aligned), total ~75 MB
    size_t off = 0;
    auto alloc = [&](size_t bytes) { size_t o = off; off = (off + bytes + 255) & ~(size_t)255; return o; };
    u32*    flags    = (u32*)((char*)d_ws + alloc(256));
    u16*    w0t      = (u16*)((char*)d_ws + alloc(128 * 128 * 2));
    u16*    w1t      = (u16*)((char*)d_ws + alloc(96 * 128 * 2));
    u16*    w0tg     = (u16*)((char*)d_ws + alloc(128 * 128 * 2));
    u16*    w1tg     = (u16*)((char*)d_ws + alloc(96 * 128 * 2));
    u16*    hw0t     = (u16*)((char*)d_ws + alloc(64 * 128 * 2));
    u32*    binCur   = (u32*)((char*)d_ws + alloc((size_t)N * 4));
    u32*    dstStart = (u32*)((char*)d_ws + alloc((size_t)(N + 1) * 4));
    u32*    blkSum   = (u32*)((char*)d_ws + alloc((size_t)(nBlkScan + 1) * 4));
    u16*    agg      = (u16*)((char*)d_ws + alloc((size_t)N * 96 * 2));
    u32*    eraw     = (u32*)((char*)d_ws + alloc((size_t)nE * 4));
    u32*    edges    = (u32*)((char*)d_ws + alloc((size_t)nE * 4));
    u16*    pbuf     = (u16*)((char*)d_ws + alloc((size_t)2 * ntileE * 96 * 2));
    u16*    yubuf    = (u16*)((char*)d_ws + alloc((size_t)N * 128 * 2));
    float*  vbbuf    = (float*)((char*)d_ws + alloc((size_t)N * 128 * 4));

    k_detect<<<1, 64, 0, stream>>>((const u32*)x, (const u32*)ei, flags);
    k_prep<<<256, 256, 0, stream>>>(fw0, fw1, gw0, gw1, hw0, w0t, w1t, w0tg, w1tg, hw0t,
                                    flags, (u32*)agg, N * 48, binCur, N);
    k_cvt<<<1024, 256, 0, stream>>>((const u32*)ei, eraw, binCur, flags, nE, N);
    k_scanA<<<nBlkScan, 256, 0, stream>>>(binCur, blkSum, N);
    k_scanC<<<nBlkScan, 256, 0, stream>>>(binCur, blkSum, binCur, dstStart, N, (u32)nE);
    k_scatter<<<1024, 256, 0, stream>>>(eraw, binCur, edges, nE);
    int yGrid = (N + 63) / 64;
    k_yd<<<yGrid, 256, 0, stream>>>(x, pos, w0t, hw0t, hb0, hw1, hb1, fw0, fb0,
                                    yubuf, vbbuf, flags, N);
    k_edge<<<1024, 256, 0, stream>>>(yubuf, (const float4*)vbbuf, edges, w1t, fb1, flags,
                                     agg, pbuf, nE);
    k_node<<<yGrid, 256, 0, stream>>>(x, agg, dstStart, pbuf, w0tg, w1tg, gb0, gb1, fb1,
                                      d_out, flags, N, nE);
}

// Round 13
// 330.134 us; speedup vs baseline: 1.0892x; 1.0892x over previous
//
#include <hip/hip_runtime.h>
#include <hip/hip_bf16.h>

typedef unsigned short u16;
typedef unsigned int u32;
typedef __bf16 bf16x8 __attribute__((ext_vector_type(8)));
typedef float f32x4 __attribute__((ext_vector_type(4)));

__device__ __forceinline__ float bf2f(u16 h) { return __uint_as_float(((u32)h) << 16); }
__device__ __forceinline__ u16 f2bf(float f) {
    u32 u = __float_as_uint(f);
    u32 r = u + 0x7FFFu + ((u >> 16) & 1u);   // round-to-nearest-even
    return (u16)(r >> 16);
}
// HW packed f32->bf16 (RNE, identical to f2bf): 1 instruction per pair
__device__ __forceinline__ u32 cvtpk(float lo, float hi) {
    u32 r;
    asm("v_cvt_pk_bf16_f32 %0, %1, %2" : "=v"(r) : "v"(lo), "v"(hi));
    return r;
}
__device__ __forceinline__ u16 cvt1(float v) { return (u16)cvtpk(v, v); }
__device__ __forceinline__ void unpack8(const u16* p, float* b) {
    uint4 v = *(const uint4*)p;
    b[0] = bf2f((u16)(v.x & 0xFFFF)); b[1] = bf2f((u16)(v.x >> 16));
    b[2] = bf2f((u16)(v.y & 0xFFFF)); b[3] = bf2f((u16)(v.y >> 16));
    b[4] = bf2f((u16)(v.z & 0xFFFF)); b[5] = bf2f((u16)(v.z >> 16));
    b[6] = bf2f((u16)(v.w & 0xFFFF)); b[7] = bf2f((u16)(v.w >> 16));
}
__device__ __forceinline__ float ldf(int bf, const void* p, long i) {
    return bf ? bf2f(((const u16*)p)[i]) : ((const float*)p)[i];
}

// -------- k_prep: inline dtype detect (per-block, redundant) + flags + zeroing + ALL weight transposes --------
__global__ void k_prep(const u32* __restrict__ xw, const u32* __restrict__ eiw,
                       const void* __restrict__ fw0, const void* __restrict__ fw1,
                       const void* __restrict__ gw0, const void* __restrict__ gw1,
                       const void* __restrict__ hw0,
                       u16* __restrict__ w0t, u16* __restrict__ w1t,
                       u16* __restrict__ w0tg, u16* __restrict__ w1tg, u16* __restrict__ hw0t,
                       u32* __restrict__ flags,
                       u32* __restrict__ z1, int nz1, u32* __restrict__ z2, int nz2) {
    __shared__ u32 fl[2];
    int tid = threadIdx.x;
    if (tid < 64) {
        int c = 0;
        for (int i = tid; i < 256; i += 64) {
            u32 e = (xw[i] >> 7) & 0xFF;
            if (e >= 96 && e <= 160) c++;
        }
#pragma unroll
        for (int d = 1; d < 64; d <<= 1) c += __shfl_xor(c, d);
        int z = (eiw[2 * tid + 1] == 0u) ? 1 : 0;
#pragma unroll
        for (int d = 1; d < 64; d <<= 1) z += __shfl_xor(z, d);
        if (tid == 0) { fl[0] = (c >= 192) ? 1u : 0u; fl[1] = (z >= 48) ? 1u : 0u; }
    }
    __syncthreads();
    const int bf = (int)fl[0];
    if (blockIdx.x == 0 && tid == 0) { flags[0] = fl[0]; flags[1] = fl[1]; }
    int gid = blockIdx.x * blockDim.x + tid;
    int stride = gridDim.x * blockDim.x;
    for (int i = gid; i < nz1; i += stride) z1[i] = 0u;
    for (int i = gid; i < nz2; i += stride) z2[i] = 0u;
    for (int i = gid; i < 128 * 128; i += stride) {
        int c = i >> 7, kp = i & 127;
        float vf = (kp < 96) ? ldf(bf, fw0, (long)(kp + 3) * 128 + c) : 0.f;
        w0t[i] = f2bf(vf);
        float vg = (kp < 96) ? ldf(bf, gw0, (long)kp * 128 + c) : 0.f;
        w0tg[i] = f2bf(vg);
    }
    for (int i = gid; i < 96 * 128; i += stride) {
        int c = i >> 7, k = i & 127;
        w1t[i]  = f2bf(ldf(bf, fw1, (long)k * 96 + c));
        w1tg[i] = f2bf(ldf(bf, gw1, (long)k * 96 + c));
    }
    for (int i = gid; i < 64 * 128; i += stride) {
        int c = i >> 7, kp = i & 127;
        float v = (kp < 96) ? ldf(bf, hw0, (long)kp * 64 + c) : 0.f;
        hw0t[i] = f2bf(v);
    }
}

// -------- k_cvt: ei -> packed u32 (src | dst<<16) + within-dst rank + dst histogram.  N <= 65536. --------
__global__ void k_cvt(const u32* __restrict__ ei, u32* __restrict__ eraw, u32* __restrict__ rank,
                      u32* __restrict__ hist, const u32* __restrict__ flags, int nE, int N) {
    u32 i64f = flags[1];
    for (long e = blockIdx.x * blockDim.x + threadIdx.x; e < nE; e += (long)gridDim.x * blockDim.x) {
        int src, dst;
        if (i64f) { src = (int)ei[2 * e]; dst = (int)ei[2 * ((long)nE + e)]; }
        else      { src = (int)ei[e];     dst = (int)ei[(long)nE + e]; }
        src = min(max(src, 0), N - 1);
        dst = min(max(dst, 0), N - 1);
        eraw[e] = (u32)src | ((u32)dst << 16);
        rank[e] = atomicAdd(&hist[dst], 1u);
    }
}

// -------- k_scanF: fused exclusive scan, one kernel.  hist read-only; writes dstart (+tail). --------
__global__ __launch_bounds__(256)
void k_scanF(const u32* __restrict__ hist, u32* __restrict__ dstart, int n, u32 total) {
    __shared__ u32 a[256];
    int tid = threadIdx.x;
    long lim = (long)blockIdx.x << 10;
    u32 s0 = 0;
    for (long i = tid; i < lim; i += 256) s0 += hist[i];
    a[tid] = s0;
    __syncthreads();
    for (int d = 128; d > 0; d >>= 1) {
        if (tid < d) a[tid] += a[tid + d];
        __syncthreads();
    }
    u32 boff = a[0];
    __syncthreads();
    int base = (int)(blockIdx.x << 10) + tid * 4;
    u32 e4[4];
    u32 ts = 0;
#pragma unroll
    for (int j = 0; j < 4; j++) {
        int idx = base + j;
        e4[j] = (idx < n) ? hist[idx] : 0u;
        ts += e4[j];
    }
    a[tid] = ts;
    __syncthreads();
    for (int d = 1; d < 256; d <<= 1) {
        u32 t = (tid >= d) ? a[tid - d] : 0u;
        __syncthreads();
        a[tid] += t;
        __syncthreads();
    }
    u32 off = boff + a[tid] - ts;
#pragma unroll
    for (int j = 0; j < 4; j++) {
        int idx = base + j;
        if (idx < n) { dstart[idx] = off; off += e4[j]; }
    }
    if (blockIdx.x == 0 && tid == 0) dstart[n] = total;
}

// -------- K_YDSC: atomic-free edge scatter (hidden under MFMA) + fused per-node precompute --------
// scatter: edges[dstart[dst] + rank[e]] = eraw[e]   (no atomics, fire-and-forget stores)
// delta = mlp_h(x); yu = x @ fw0[3:99] + pos . fw0[0:3] (bf16); vb = (delta - pos) . fw0[0:3] + fb0 (f32)
__global__ __launch_bounds__(256)
void k_ydsc(const void* __restrict__ x, const void* __restrict__ pos,
            const u16* __restrict__ w0t, const u16* __restrict__ hw0t,
            const void* __restrict__ hb0, const void* __restrict__ hw1, const void* __restrict__ hb1,
            const void* __restrict__ fw0, const void* __restrict__ fb0,
            u16* __restrict__ yu, float* __restrict__ vbO,
            const u32* __restrict__ flags, int N,
            const u32* __restrict__ eraw, const u32* __restrict__ rank,
            const u32* __restrict__ dstart, u32* __restrict__ edges, int nE)
{
    const int bf = (int)flags[0];
    __shared__ __align__(16) char arena[16384];
    __shared__ float posS[64][4];
    __shared__ float h1S[64][68];
    __shared__ float w0rS[384];
    __shared__ float b0fS[128];
    __shared__ float hb0S[64];
    __shared__ float hw1S[192];
    __shared__ float hb1S[3];
    int tid = threadIdx.x;
    // ---- scatter phase first: stores drain under the MFMA work below ----
    {
        long stride = (long)gridDim.x * 256;
        for (long e = (long)blockIdx.x * 256 + tid; e < nE; e += stride) {
            u32 ed = eraw[e];
            edges[dstart[ed >> 16] + rank[e]] = ed;
        }
    }
    for (int i = tid; i < 384; i += 256) w0rS[i] = ldf(bf, fw0, i);
    if (tid < 128) b0fS[tid] = ldf(bf, fb0, tid);
    if (tid < 64)  hb0S[tid] = ldf(bf, hb0, tid);
    if (tid < 192) hw1S[tid] = ldf(bf, hw1, tid);
    if (tid < 3)   hb1S[tid] = ldf(bf, hb1, tid);
    __syncthreads();

    const int lane = tid & 63;
    const int wid  = tid >> 6;
    const int mrow0 = wid * 16;
    const int r16  = lane & 15;
    const int arow = mrow0 + r16;
    const int kgrp = lane >> 4;
    const int srow = tid >> 2;
    const int q = tid & 3;
    const int ssw = (srow & 7) << 4;

    int ntile = (N + 63) / 64;
    for (int t = blockIdx.x; t < ntile; t += gridDim.x) {
        {   // stage x rows -> swizzled arena bf16; pos -> posS
            int n = t * 64 + srow;
            if (tid < 64) {
                int n2 = t * 64 + tid;
                posS[tid][0] = (n2 < N) ? ldf(bf, pos, (long)n2 * 3 + 0) : 0.f;
                posS[tid][1] = (n2 < N) ? ldf(bf, pos, (long)n2 * 3 + 1) : 0.f;
                posS[tid][2] = (n2 < N) ? ldf(bf, pos, (long)n2 * 3 + 2) : 0.f;
            }
            if (n < N) {
                if (bf) {
                    const uint4* ar = (const uint4*)((const u16*)x + (size_t)n * 96);
#pragma unroll
                    for (int j = 0; j < 3; j++) {
                        int c = q * 3 + j;
                        *(uint4*)(arena + srow * 256 + ((c * 16) ^ ssw)) = ar[c];
                    }
                } else {
                    const float4* xp = (const float4*)((const float*)x + (size_t)n * 96);
#pragma unroll
                    for (int j = 0; j < 3; j++) {
                        int c = q * 3 + j;
                        float4 v0 = xp[2 * c], v1 = xp[2 * c + 1];
                        *(uint4*)(arena + srow * 256 + ((c * 16) ^ ssw)) =
                            make_uint4(cvtpk(v0.x, v0.y), cvtpk(v0.z, v0.w),
                                       cvtpk(v1.x, v1.y), cvtpk(v1.z, v1.w));
                    }
                }
            } else {
#pragma unroll
                for (int j = 0; j < 3; j++)
                    *(uint4*)(arena + srow * 256 + (((q * 3 + j) * 16) ^ ssw)) = make_uint4(0u, 0u, 0u, 0u);
            }
        }
        __syncthreads();
        int sw = (arow & 7) << 4;
        bf16x8 a0 = *(const bf16x8*)(arena + arow * 256 + ((0   + kgrp * 16) ^ sw));
        bf16x8 a1 = *(const bf16x8*)(arena + arow * 256 + ((64  + kgrp * 16) ^ sw));
        bf16x8 a2 = *(const bf16x8*)(arena + arow * 256 + ((128 + kgrp * 16) ^ sw));
        // ---- GEMM-delta layer1: h1 = relu(x @ hw0 + hb0), N=64 ----
        f32x4 accd[4];
#pragma unroll
        for (int nt = 0; nt < 4; nt++) {
#pragma unroll
            for (int r = 0; r < 4; r++) accd[nt][r] = 0.f;
        }
#pragma unroll
        for (int nt = 0; nt < 4; nt++) {
            const u16* wp = hw0t + (long)(nt * 16 + r16) * 128 + kgrp * 8;
            accd[nt] = __builtin_amdgcn_mfma_f32_16x16x32_bf16(a0, *(const bf16x8*)(wp),      accd[nt], 0, 0, 0);
            accd[nt] = __builtin_amdgcn_mfma_f32_16x16x32_bf16(a1, *(const bf16x8*)(wp + 32), accd[nt], 0, 0, 0);
            accd[nt] = __builtin_amdgcn_mfma_f32_16x16x32_bf16(a2, *(const bf16x8*)(wp + 64), accd[nt], 0, 0, 0);
        }
#pragma unroll
        for (int nt = 0; nt < 4; nt++) {
            int col = nt * 16 + r16;
#pragma unroll
            for (int r = 0; r < 4; r++)
                h1S[mrow0 + kgrp * 4 + r][col] = fmaxf(accd[nt][r] + hb0S[col], 0.f);
        }
        // ---- GEMM-y: y = x @ w0t (f-MLP cols), N=128 ----
        f32x4 acc[8];
#pragma unroll
        for (int nt = 0; nt < 8; nt++) {
#pragma unroll
            for (int r = 0; r < 4; r++) acc[nt][r] = 0.f;
        }
#pragma unroll
        for (int nt = 0; nt < 8; nt++) {
            const u16* wp = w0t + (long)(nt * 16 + r16) * 128 + kgrp * 8;
            acc[nt] = __builtin_amdgcn_mfma_f32_16x16x32_bf16(a0, *(const bf16x8*)(wp),      acc[nt], 0, 0, 0);
            acc[nt] = __builtin_amdgcn_mfma_f32_16x16x32_bf16(a1, *(const bf16x8*)(wp + 32), acc[nt], 0, 0, 0);
            acc[nt] = __builtin_amdgcn_mfma_f32_16x16x32_bf16(a2, *(const bf16x8*)(wp + 64), acc[nt], 0, 0, 0);
        }
        __syncthreads();   // h1S complete
        // ---- delta layer2 (64->3) + vb epilogue ----
        {
            int nl = tid >> 2;
            int n = t * 64 + nl;
            float d0 = hb1S[0], d1 = hb1S[1], d2 = hb1S[2];
#pragma unroll 8
            for (int j = 0; j < 64; j++) {
                float hv = h1S[nl][j];
                d0 += hv * hw1S[j * 3 + 0];
                d1 += hv * hw1S[j * 3 + 1];
                d2 += hv * hw1S[j * 3 + 2];
            }
            float p0 = d0 - posS[nl][0], p1 = d1 - posS[nl][1], p2 = d2 - posS[nl][2];
            if (n < N) {
                float* vrow = vbO + (size_t)n * 128 + q * 32;
#pragma unroll
                for (int c4 = 0; c4 < 8; c4++) {
                    float4 o;
#pragma unroll
                    for (int k = 0; k < 4; k++) {
                        int col = q * 32 + c4 * 4 + k;
                        float v = p0 * w0rS[col] + p1 * w0rS[128 + col] + p2 * w0rS[256 + col] + b0fS[col];
                        ((float*)&o)[k] = v;
                    }
                    *(float4*)(vrow + c4 * 4) = o;
                }
            }
        }
        // ---- yu epilogue: yu = y + pos . w0r ----
#pragma unroll
        for (int nt = 0; nt < 8; nt++) {
            int col = nt * 16 + r16;
            float wr0 = w0rS[col], wr1 = w0rS[128 + col], wr2 = w0rS[256 + col];
#pragma unroll
            for (int r = 0; r < 4; r++) {
                int row = mrow0 + kgrp * 4 + r;
                int n2 = t * 64 + row;
                if (n2 < N) {
                    float u = posS[row][0] * wr0 + posS[row][1] * wr1 + posS[row][2] * wr2;
                    yu[(size_t)n2 * 128 + col] = cvt1(acc[nt][r] + u);
                }
            }
        }
        __syncthreads();
    }
}

// -------- K2: edge MLP: h = relu(yu[src] + vb[dst]); GEMM2 MFMA; zero atomics --------
// edges packed u32: src = e & 0xFFFF, dst = e >> 16 (N <= 65536)
__global__ __launch_bounds__(256)
void k_edge(const u16* __restrict__ yu, const float4* __restrict__ vb,
            const u32* __restrict__ edges, const u16* __restrict__ w1t,
            const void* __restrict__ fb1, const u32* __restrict__ flags,
            u16* __restrict__ agg, u16* __restrict__ pbuf, int nE)
{
    const int bf = (int)flags[0];
    __shared__ __align__(16) u16 w1S[96 * 128];      // 24576 B, XOR-swizzled rows of 256 B
    __shared__ float b1s[96];
    __shared__ int dstS[4][16];
    __shared__ __align__(16) u16 outS[4][16 * 98];   // bf16 out, stride 98
    int tid = threadIdx.x;
    for (int i = tid; i < 96 * 64; i += 256) {
        int col = i >> 6, kp = i & 63;
        u32 v = ((const u32*)w1t)[i];
        *(u32*)((char*)w1S + col * 256 + ((kp * 4) ^ ((col & 7) << 4))) = v;
    }
    if (tid < 96) b1s[tid] = ldf(bf, fb1, tid);
    __syncthreads();   // one-time staging only

    const int lane = tid & 63;
    const int wid  = tid >> 6;
    const int r16  = lane & 15;
    const int kgrp = lane >> 4;
    const int ntile = (nE + 15) / 16;
    const size_t tailSlot = (size_t)ntile * 96;
    u16* const outSw = outS[wid];

    const int stride = (int)gridDim.x * 4;
    int t = (int)blockIdx.x * 4 + wid;

    // pipeline regs
    u32 ce = 0u, ne = 0u;
    uint4 G[4];                        // yu fragments for tile t

    auto issueGather = [&](u32 src) {
        const u16* yp = yu + (size_t)src * 128 + kgrp * 8;
#pragma unroll
        for (int f = 0; f < 4; f++) G[f] = *(const uint4*)(yp + f * 32);
    };

    if (t < ntile) {
        long E = min((long)t * 16 + r16, (long)nE - 1);
        ce = edges[E];
        issueGather(ce & 0xFFFFu);
        int tn = t + stride;
        if (tn < ntile) {
            long En = min((long)tn * 16 + r16, (long)nE - 1);
            ne = edges[En];
        }
    }

    for (; t < ntile; t += stride) {
        asm volatile("" ::: "memory");
        if (kgrp == 3) dstS[wid][r16] = (int)(ce >> 16);
        // neighbor dsts for boundary-run classification
        int dprevV = -1, dnextV = -1;
        {
            long e0 = (long)t * 16;
            if (e0 > 0) dprevV = (int)(edges[e0 - 1] >> 16);
            if (e0 + 16 < (long)nE) dnextV = (int)(edges[e0 + 16] >> 16);
        }
        // ---- h fragments: relu(yu + vb), lane-local; vb JIT loads (L1-resident runs) ----
        const float4* vbp = vb + (size_t)(ce >> 16) * 32 + kgrp * 2;
        bf16x8 hf[4];
#pragma unroll
        for (int f = 0; f < 4; f++) {
            float4 v0 = vbp[f * 8], v1 = vbp[f * 8 + 1];
            u32 w0 = G[f].x, w1 = G[f].y, w2 = G[f].z, w3 = G[f].w;
            u32 hw[4];
            hw[0] = cvtpk(fmaxf(bf2f((u16)(w0 & 0xFFFF)) + v0.x, 0.f),
                          fmaxf(bf2f((u16)(w0 >> 16))    + v0.y, 0.f));
            hw[1] = cvtpk(fmaxf(bf2f((u16)(w1 & 0xFFFF)) + v0.z, 0.f),
                          fmaxf(bf2f((u16)(w1 >> 16))    + v0.w, 0.f));
            hw[2] = cvtpk(fmaxf(bf2f((u16)(w2 & 0xFFFF)) + v1.x, 0.f),
                          fmaxf(bf2f((u16)(w2 >> 16))    + v1.y, 0.f));
            hw[3] = cvtpk(fmaxf(bf2f((u16)(w3 & 0xFFFF)) + v1.z, 0.f),
                          fmaxf(bf2f((u16)(w3 >> 16))    + v1.w, 0.f));
            uint4 hv = make_uint4(hw[0], hw[1], hw[2], hw[3]);
            hf[f] = *(const bf16x8*)&hv;
        }
        // ---- G is dead: issue next tile's gathers + indices (depth-1 pipeline) ----
        u32 c2e = ne;
        {
            int tn = t + stride;
            if (tn < ntile) {
                issueGather(c2e & 0xFFFFu);
                int tn2 = tn + stride;
                if (tn2 < ntile) {
                    long E2 = min((long)tn2 * 16 + r16, (long)nE - 1);
                    ne = edges[E2];
                }
            }
        }
        // ---- GEMM2: e2 = h @ W1 (K=128, N=96), W1 from swizzled LDS ----
        f32x4 acc2[6];
#pragma unroll
        for (int nt = 0; nt < 6; nt++) {
#pragma unroll
            for (int r = 0; r < 4; r++) acc2[nt][r] = 0.f;
        }
#pragma unroll
        for (int nt = 0; nt < 6; nt++) {
            int colr = nt * 16 + r16;
            const char* wb = (const char*)w1S + colr * 256;
            int csw = (colr & 7) << 4;
            acc2[nt] = __builtin_amdgcn_mfma_f32_16x16x32_bf16(hf[0], *(const bf16x8*)(wb + ((kgrp * 16)       ^ csw)), acc2[nt], 0, 0, 0);
            acc2[nt] = __builtin_amdgcn_mfma_f32_16x16x32_bf16(hf[1], *(const bf16x8*)(wb + ((kgrp * 16 + 64)  ^ csw)), acc2[nt], 0, 0, 0);
            acc2[nt] = __builtin_amdgcn_mfma_f32_16x16x32_bf16(hf[2], *(const bf16x8*)(wb + ((kgrp * 16 + 128) ^ csw)), acc2[nt], 0, 0, 0);
            acc2[nt] = __builtin_amdgcn_mfma_f32_16x16x32_bf16(hf[3], *(const bf16x8*)(wb + ((kgrp * 16 + 192) ^ csw)), acc2[nt], 0, 0, 0);
        }
        // out (bf16) -> wave-local stride-98 overlay
#pragma unroll
        for (int nt = 0; nt < 6; nt++) {
            int col = nt * 16 + r16;
#pragma unroll
            for (int r = 0; r < 4; r++) {
                int row = kgrp * 4 + r;
                outSw[row * 98 + col] = cvt1(acc2[nt][r]);
            }
        }
        // ---- run-scan: plain stores (complete runs -> agg; boundary -> pbuf) ----
        {
            int d0s = dstS[wid][0], d15s = dstS[wid][15];
            bool extL = (dprevV == d0s);
            bool extR = (dnextV == d15s);
#pragma unroll
            for (int p = 0; p < 2; p++) {
                int col = p * 64 + lane;
                if (p == 0 || lane < 32) {
                    float b1c = b1s[col];
                    int curd = d0s;
                    int r0 = 0;
                    float m = bf2f(outSw[col]);
#pragma unroll
                    for (int row = 1; row < 16; row++) {
                        float v = bf2f(outSw[row * 98 + col]);
                        int d = dstS[wid][row];
                        if (d != curd) {
                            if (r0 == 0 && extL) pbuf[(size_t)t * 96 + col] = cvt1(m);
                            else agg[(size_t)curd * 96 + col] = cvt1(m + b1c);
                            curd = d; r0 = row; m = v;
                        } else m = fmaxf(m, v);
                    }
                    bool pl = (r0 == 0) && extL;
                    if (pl || extR) {
                        size_t slot = (r0 == 0) ? 0 : tailSlot;
                        pbuf[slot + (size_t)t * 96 + col] = cvt1(m);
                    } else agg[(size_t)curd * 96 + col] = cvt1(m + b1c);
                }
            }
        }
        ce = c2e;
    }
}

// -------- K3: out = x + mlp_g(agg)  (96 -> 128 relu -> 96), MFMA; inline pbuf merge --------
__global__ __launch_bounds__(256)
void k_node(const void* __restrict__ x, const u16* __restrict__ agg,
            const u32* __restrict__ dstart, const u16* __restrict__ pbuf,
            const u16* __restrict__ w0tg, const u16* __restrict__ w1tg,
            const void* __restrict__ gb0, const void* __restrict__ gb1,
            const void* __restrict__ fb1,
            void* __restrict__ out, const u32* __restrict__ flags, int N, int nE)
{
    const int bf = (int)flags[0];
    __shared__ __align__(16) char arena[32768];
    __shared__ float b0s[128];
    __shared__ float b1s[96];
    __shared__ float b1f[96];
    int tid = threadIdx.x;
    if (tid < 128) b0s[tid] = ldf(bf, gb0, tid);
    if (tid < 96)  b1s[tid] = ldf(bf, gb1, tid);
    if (tid < 96)  b1f[tid] = ldf(bf, fb1, tid);
    __syncthreads();

    const int lane = tid & 63;
    const int wid  = tid >> 6;
    const int mrow0 = wid * 16;
    const int arow = mrow0 + (lane & 15);
    const int kgrp = lane >> 4;
    const int srow = tid >> 2;
    const int q = tid & 3;
    const int ssw = (srow & 7) << 4;
    const int ntileE = (nE + 15) / 16;

    float b0v[8];
#pragma unroll
    for (int nt = 0; nt < 8; nt++) b0v[nt] = b0s[nt * 16 + (lane & 15)];

    auto outOff = [](int row, int col) {
        int j = row & 15, w2 = row >> 4;
        int base = (j < 8) ? (w2 * 4096 + j * 512) : (16384 + w2 * 4096 + (j - 8) * 512);
        return base + ((col ^ (((row >> 2) & 3) << 4)) << 2);
    };

    int ntile = (N + 63) / 64;
    for (int t = blockIdx.x; t < ntile; t += gridDim.x) {
        asm volatile("" ::: "memory");
        {   // stage agg row: single-tile/empty -> agg; multi-tile -> merge pbuf partials (+fb1)
            int n = t * 64 + srow;
            if (n < N) {
                u32 s = dstart[n], e = dstart[n + 1];
                int t0 = (int)(s >> 4);
                int t1 = (e > s) ? (int)((e - 1) >> 4) : t0;
                if (e > s && t0 != t1) {
                    const u16* pH = pbuf;
                    const u16* pT = pbuf + (size_t)ntileE * 96;
                    const u16* first = ((s & 15u) == 0u) ? pH : pT;
#pragma unroll
                    for (int j = 0; j < 3; j++) {
                        int c = q * 3 + j;
                        float mf[8];
                        unpack8(first + (size_t)t0 * 96 + c * 8, mf);
                        for (int tt = t0 + 1; tt <= t1; tt++) {
                            float tf[8];
                            unpack8(pH + (size_t)tt * 96 + c * 8, tf);
#pragma unroll
                            for (int k = 0; k < 8; k++) mf[k] = fmaxf(mf[k], tf[k]);
                        }
                        uint4 o;
                        o.x = cvtpk(mf[0] + b1f[c * 8 + 0], mf[1] + b1f[c * 8 + 1]);
                        o.y = cvtpk(mf[2] + b1f[c * 8 + 2], mf[3] + b1f[c * 8 + 3]);
                        o.z = cvtpk(mf[4] + b1f[c * 8 + 4], mf[5] + b1f[c * 8 + 5]);
                        o.w = cvtpk(mf[6] + b1f[c * 8 + 6], mf[7] + b1f[c * 8 + 7]);
                        *(uint4*)(arena + srow * 256 + ((c * 16) ^ ssw)) = o;
                    }
                } else {
                    const uint4* ar = (const uint4*)(agg + (size_t)n * 96);
#pragma unroll
                    for (int j = 0; j < 3; j++) {
                        int c = q * 3 + j;
                        *(uint4*)(arena + srow * 256 + ((c * 16) ^ ssw)) = ar[c];
                    }
                }
            } else {
#pragma unroll
                for (int j = 0; j < 3; j++)
                    *(uint4*)(arena + srow * 256 + (((q * 3 + j) * 16) ^ ssw)) = make_uint4(0u, 0u, 0u, 0u);
            }
        }
        __syncthreads();
        int sw = (arow & 7) << 4;
        bf16x8 a0 = *(const bf16x8*)(arena + arow * 256 + ((0   + kgrp * 16) ^ sw));
        bf16x8 a1 = *(const bf16x8*)(arena + arow * 256 + ((64  + kgrp * 16) ^ sw));
        bf16x8 a2 = *(const bf16x8*)(arena + arow * 256 + ((128 + kgrp * 16) ^ sw));
        f32x4 acc[8];
#pragma unroll
        for (int nt = 0; nt < 8; nt++) {
#pragma unroll
            for (int r = 0; r < 4; r++) acc[nt][r] = 0.f;
        }
#pragma unroll
        for (int nt = 0; nt < 8; nt++) {
            const u16* wp = w0tg + (long)(nt * 16 + (lane & 15)) * 128 + kgrp * 8;
            acc[nt] = __builtin_amdgcn_mfma_f32_16x16x32_bf16(a0, *(const bf16x8*)(wp),      acc[nt], 0, 0, 0);
            acc[nt] = __builtin_amdgcn_mfma_f32_16x16x32_bf16(a1, *(const bf16x8*)(wp + 32), acc[nt], 0, 0, 0);
            acc[nt] = __builtin_amdgcn_mfma_f32_16x16x32_bf16(a2, *(const bf16x8*)(wp + 64), acc[nt], 0, 0, 0);
        }
#pragma unroll
        for (int nt = 0; nt < 8; nt++) {
            int col = nt * 16 + (lane & 15);
#pragma unroll
            for (int r = 0; r < 4; r++) {
                int row = mrow0 + kgrp * 4 + r;
                float hv = fmaxf(acc[nt][r] + b0v[nt], 0.f);
                *(u16*)(arena + 16384 + row * 256 + ((col * 2) ^ ((row & 7) << 4))) = cvt1(hv);
            }
        }
        bf16x8 h0 = *(const bf16x8*)(arena + 16384 + arow * 256 + ((0   + kgrp * 16) ^ sw));
        bf16x8 h1 = *(const bf16x8*)(arena + 16384 + arow * 256 + ((64  + kgrp * 16) ^ sw));
        bf16x8 h2 = *(const bf16x8*)(arena + 16384 + arow * 256 + ((128 + kgrp * 16) ^ sw));
        bf16x8 h3 = *(const bf16x8*)(arena + 16384 + arow * 256 + ((192 + kgrp * 16) ^ sw));
        f32x4 acc2[6];
#pragma unroll
        for (int nt = 0; nt < 6; nt++) {
#pragma unroll
            for (int r = 0; r < 4; r++) acc2[nt][r] = 0.f;
        }
#pragma unroll
        for (int nt = 0; nt < 6; nt++) {
            const u16* wp = w1tg + (long)(nt * 16 + (lane & 15)) * 128 + kgrp * 8;
            acc2[nt] = __builtin_amdgcn_mfma_f32_16x16x32_bf16(h0, *(const bf16x8*)(wp),      acc2[nt], 0, 0, 0);
            acc2[nt] = __builtin_amdgcn_mfma_f32_16x16x32_bf16(h1, *(const bf16x8*)(wp + 32), acc2[nt], 0, 0, 0);
            acc2[nt] = __builtin_amdgcn_mfma_f32_16x16x32_bf16(h2, *(const bf16x8*)(wp + 64), acc2[nt], 0, 0, 0);
            acc2[nt] = __builtin_amdgcn_mfma_f32_16x16x32_bf16(h3, *(const bf16x8*)(wp + 96), acc2[nt], 0, 0, 0);
        }
#pragma unroll
        for (int nt = 0; nt < 6; nt++) {
            int col = nt * 16 + (lane & 15);
#pragma unroll
            for (int r = 0; r < 4; r++) {
                int row = mrow0 + kgrp * 4 + r;
                *(float*)(arena + outOff(row, col)) = acc2[nt][r];
            }
        }
        __syncthreads();
        {
            int n = t * 64 + srow;
            if (n < N) {
                float v[24];
#pragma unroll
                for (int c = 0; c < 24; c++) v[c] = *(const float*)(arena + outOff(srow, q * 24 + c));
                if (bf) {
                    u16* orow = (u16*)out + (size_t)n * 96 + q * 24;
#pragma unroll
                    for (int j = 0; j < 3; j++) {
                        float xv[8];
                        unpack8((const u16*)x + (size_t)n * 96 + q * 24 + j * 8, xv);
                        uint4 o;
                        o.x = cvtpk(xv[0] + v[j * 8 + 0] + b1s[q * 24 + j * 8 + 0],
                                    xv[1] + v[j * 8 + 1] + b1s[q * 24 + j * 8 + 1]);
                        o.y = cvtpk(xv[2] + v[j * 8 + 2] + b1s[q * 24 + j * 8 + 2],
                                    xv[3] + v[j * 8 + 3] + b1s[q * 24 + j * 8 + 3]);
                        o.z = cvtpk(xv[4] + v[j * 8 + 4] + b1s[q * 24 + j * 8 + 4],
                                    xv[5] + v[j * 8 + 5] + b1s[q * 24 + j * 8 + 5]);
                        o.w = cvtpk(xv[6] + v[j * 8 + 6] + b1s[q * 24 + j * 8 + 6],
                                    xv[7] + v[j * 8 + 7] + b1s[q * 24 + j * 8 + 7]);
                        *(uint4*)(orow + j * 8) = o;
                    }
                } else {
                    const float* xr = (const float*)x + (size_t)n * 96 + q * 24;
                    float* orow = (float*)out + (size_t)n * 96 + q * 24;
#pragma unroll
                    for (int j = 0; j < 6; j++) {
                        float4 xv = ((const float4*)xr)[j];
                        float4 o;
                        o.x = xv.x + v[4 * j + 0] + b1s[q * 24 + 4 * j + 0];
                        o.y = xv.y + v[4 * j + 1] + b1s[q * 24 + 4 * j + 1];
                        o.z = xv.z + v[4 * j + 2] + b1s[q * 24 + 4 * j + 2];
                        o.w = xv.w + v[4 * j + 3] + b1s[q * 24 + 4 * j + 3];
                        ((float4*)orow)[j] = o;
                    }
                }
            }
        }
        __syncthreads();
    }
}

extern "C" void kernel_launch(void* const* d_in, const int* in_sizes, int n_in,
                              void* d_out, int out_size, void* d_ws, size_t ws_size,
                              hipStream_t stream) {
    const void* x   = d_in[0];
    const void* pos = d_in[1];
    const void* ei  = d_in[2];
    const void* hw0 = d_in[3];
    const void* hb0 = d_in[4];
    const void* hw1 = d_in[5];
    const void* hb1 = d_in[6];
    const void* fw0 = d_in[7];
    const void* fb0 = d_in[8];
    const void* fw1 = d_in[9];
    const void* fb1 = d_in[10];
    const void* gw0 = d_in[11];
    const void* gb0 = d_in[12];
    const void* gw1 = d_in[13];
    const void* gb1 = d_in[14];

    int N  = in_sizes[0] / 96;   // 50000  (< 65536: u16 packing valid)
    int nE = in_sizes[2] / 2;    // 800000
    int ntileE = (nE + 15) / 16; // 50000
    int nBlkScan = (N + 1023) / 1024;  // 49

    // workspace layout (256B aligned), total ~79 MB
    size_t off = 0;
    auto alloc = [&](size_t bytes) { size_t o = off; off = (off + bytes + 255) & ~(size_t)255; return o; };
    u32*    flags    = (u32*)((char*)d_ws + alloc(256));
    u16*    w0t      = (u16*)((char*)d_ws + alloc(128 * 128 * 2));
    u16*    w1t      = (u16*)((char*)d_ws + alloc(96 * 128 * 2));
    u16*    w0tg     = (u16*)((char*)d_ws + alloc(128 * 128 * 2));
    u16*    w1tg     = (u16*)((char*)d_ws + alloc(96 * 128 * 2));
    u16*    hw0t     = (u16*)((char*)d_ws + alloc(64 * 128 * 2));
    u32*    hist     = (u32*)((char*)d_ws + alloc((size_t)N * 4));
    u32*    dstart   = (u32*)((char*)d_ws + alloc((size_t)(N + 1) * 4));
    u16*    agg      = (u16*)((char*)d_ws + alloc((size_t)N * 96 * 2));
    u32*    eraw     = (u32*)((char*)d_ws + alloc((size_t)nE * 4));
    u32*    rank     = (u32*)((char*)d_ws + alloc((size_t)nE * 4));
    u32*    edges    = (u32*)((char*)d_ws + alloc((size_t)nE * 4));
    u16*    pbuf     = (u16*)((char*)d_ws + alloc((size_t)2 * ntileE * 96 * 2));
    u16*    yubuf    = (u16*)((char*)d_ws + alloc((size_t)N * 128 * 2));
    float*  vbbuf    = (float*)((char*)d_ws + alloc((size_t)N * 128 * 4));

    k_prep<<<1024, 256, 0, stream>>>((const u32*)x, (const u32*)ei, fw0, fw1, gw0, gw1, hw0,
                                     w0t, w1t, w0tg, w1tg, hw0t, flags,
                                     (u32*)agg, N * 48, hist, N);
    k_cvt<<<1024, 256, 0, stream>>>((const u32*)ei, eraw, rank, hist, flags, nE, N);
    k_scanF<<<nBlkScan, 256, 0, stream>>>(hist, dstart, N, (u32)nE);
    int yGrid = (N + 63) / 64;
    k_ydsc<<<yGrid, 256, 0, stream>>>(x, pos, w0t, hw0t, hb0, hw1, hb1, fw0, fb0,
                                      yubuf, vbbuf, flags, N, eraw, rank, dstart, edges, nE);
    k_edge<<<1024, 256, 0, stream>>>(yubuf, (const float4*)vbbuf, edges, w1t, fb1, flags,
                                     agg, pbuf, nE);
    k_node<<<yGrid, 256, 0, stream>>>(x, agg, dstart, pbuf, w0tg, w1tg, gb0, gb1, fb1,
                                      d_out, flags, N, nE);
}